// Round 6
// baseline (243.864 us; speedup 1.0000x reference)
//
#include <hip/hip_runtime.h>
#include <stdint.h>

#define BB 8
#define CC 8
#define HH 512
#define WW 512
#define HWSZ (HH * WW)

typedef float v4 __attribute__((ext_vector_type(4)));

#define LOG2_CLAMP -144.26950409f   // -100 / ln2

__device__ __forceinline__ v4 aload4(const float* __restrict__ p) {
    return *(const v4* __restrict__)p;
}

__device__ __forceinline__ v4 sig4(v4 x) {
    v4 r;
#pragma unroll
    for (int i = 0; i < 4; ++i)
        r[i] = __builtin_amdgcn_rcpf(1.0f + __expf(-x[i]));
    return r;
}

__device__ __forceinline__ void mk_masks(float mh0, float mh1, float mw0, float mw3,
                                         float* A, float* B, float* C) {
    A[0]=mh0*mw0; A[1]=mh0; A[2]=mh0;     A[3]=mw0; A[4]=1.f; A[5]=mh1*mw0; A[6]=mh1; A[7]=mh1;
    B[0]=mh0;     B[1]=mh0; B[2]=mh0;     B[3]=1.f; B[4]=1.f; B[5]=mh1;     B[6]=mh1; B[7]=mh1;
    C[0]=mh0;     C[1]=mh0; C[2]=mh0*mw3; C[3]=1.f; C[4]=mw3; C[5]=mh1;     C[6]=mh1; C[7]=mh1*mw3;
}

// one row's 8 votes; accumulates POSITIVE log2 sums into Lbic/Lcon
template <bool NEED_MIN>
__device__ __forceinline__ void eval_row(
    const v4* __restrict__ cr, const v4* __restrict__ nr, uint32_t sel,
    const float* __restrict__ mkA, const float* __restrict__ mkB,
    const float* __restrict__ mkC,
    v4& glo, v4& vmin, float& Lbic, float& Lcon)
{
    const v4 one = {1.f, 1.f, 1.f, 1.f};
    v4 pb0 = one, pb1 = one, pc = one;
    v4 vsum = {0.f, 0.f, 0.f, 0.f};
    if (NEED_MIN) vmin = {1e30f, 1e30f, 1e30f, 1e30f};

#pragma unroll
    for (int k = 0; k < 8; ++k) {
        v4 s = sig4(cr[k]);
        v4 n = sig4(nr[k]);
        n[0] *= mkA[k]; n[1] *= mkB[k]; n[2] *= mkB[k]; n[3] *= mkC[k];
        v4 v = s * n;
        vsum += v;
        if (NEED_MIN) vmin = __builtin_elementwise_min(vmin, v);
        v4 av, as;
#pragma unroll
        for (int i = 0; i < 4; ++i) {
            const bool bt = (sel >> (k * 4 + i)) & 1u;
            av[i] = bt ? v[i] : 1.0f - v[i];
            as[i] = bt ? s[i] : 1.0f - s[i];
        }
        if (k < 4) pb0 *= av; else pb1 *= av;
        pc *= as;
    }
    glo = vsum * 0.125f;
#pragma unroll
    for (int i = 0; i < 4; ++i) {
        Lbic += fmaxf(__log2f(pb0[i]), LOG2_CLAMP) + fmaxf(__log2f(pb1[i]), LOG2_CLAMP);
        Lcon += fmaxf(__log2f(pc[i]), LOG2_CLAMP);
    }
}

// One input (atts or dets) over the thread's 4x2 patch. x0/x1 = center quads
// rows h/h+1; xu*/xd* = halo rows h-1/h+2 (ch 7,6,5 / 2,1,0). Column +-1 shifts
// built from own + adjacent-lane quads (__shfl); lane-edge carries fixed from
// memory (2/64 lanes, L1-hot). Shuffle garbage at image edges lands only in
// mask-zeroed elements.
template <bool NEED_MIN>
__device__ __forceinline__ void eval_input(
    const float* __restrict__ Xb,
    const v4* __restrict__ x0, const v4* __restrict__ x1,
    v4 xu7, v4 xu6, v4 xu5, v4 xd2, v4 xd1, v4 xd0,
    int offC0, int offC1, int offU, int offD, int lane,
    uint32_t sel0, uint32_t sel1,
    const float* __restrict__ mkA0, const float* __restrict__ mkB0,
    const float* __restrict__ mkC0,
    const float* __restrict__ mkA1, const float* __restrict__ mkB1,
    const float* __restrict__ mkC1,
    v4& glo0, v4& glo1, v4& vmin0, v4& vmin1, float& Lb, float& Lc)
{
    // left carries (element at col w0-1): order u7, c0_4, c1_2, c0_7, c1_4, d2
    float cm[6] = { __shfl(xu7[3],   lane - 1, 64),
                    __shfl(x0[4][3], lane - 1, 64),
                    __shfl(x1[2][3], lane - 1, 64),
                    __shfl(x0[7][3], lane - 1, 64),
                    __shfl(x1[4][3], lane - 1, 64),
                    __shfl(xd2[3],   lane - 1, 64) };
    if (lane == 0) {   // w0==0 case is mask-zeroed; address stays in-bounds (ch>=2)
        cm[0] = Xb[7 * HWSZ + offU  - 1];
        cm[1] = Xb[4 * HWSZ + offC0 - 1];
        cm[2] = Xb[2 * HWSZ + offC1 - 1];
        cm[3] = Xb[7 * HWSZ + offC0 - 1];
        cm[4] = Xb[4 * HWSZ + offC1 - 1];
        cm[5] = Xb[2 * HWSZ + offD  - 1];
    }
    // right carries (element at col w0+4): order u5, c0_3, c1_0, c0_5, c1_3, d0
    float cp[6] = { __shfl(xu5[0],   lane + 1, 64),
                    __shfl(x0[3][0], lane + 1, 64),
                    __shfl(x1[0][0], lane + 1, 64),
                    __shfl(x0[5][0], lane + 1, 64),
                    __shfl(x1[3][0], lane + 1, 64),
                    __shfl(xd0[0],   lane + 1, 64) };
    if (lane == 63) {  // w0==508 case is mask-zeroed; address stays in-bounds (ch<=5)
        cp[0] = Xb[5 * HWSZ + offU  + 4];
        cp[1] = Xb[3 * HWSZ + offC0 + 4];
        cp[2] = Xb[0 * HWSZ + offC1 + 4];
        cp[3] = Xb[5 * HWSZ + offC0 + 4];
        cp[4] = Xb[3 * HWSZ + offC1 + 4];
        cp[5] = Xb[0 * HWSZ + offD  + 4];
    }

    v4 n[8];
    // row h votes: U = halo row h-1, D = row h+1 centers (in-register)
    n[0] = (v4){cm[0], xu7[0], xu7[1], xu7[2]};
    n[1] = xu6;
    n[2] = (v4){xu5[1], xu5[2], xu5[3], cp[0]};
    n[3] = (v4){cm[1], x0[4][0], x0[4][1], x0[4][2]};
    n[4] = (v4){x0[3][1], x0[3][2], x0[3][3], cp[1]};
    n[5] = (v4){cm[2], x1[2][0], x1[2][1], x1[2][2]};
    n[6] = x1[1];
    n[7] = (v4){x1[0][1], x1[0][2], x1[0][3], cp[2]};
    eval_row<NEED_MIN>(x0, n, sel0, mkA0, mkB0, mkC0, glo0, vmin0, Lb, Lc);

    // row h+1 votes: U = row h centers (in-register), D = halo row h+2
    n[0] = (v4){cm[3], x0[7][0], x0[7][1], x0[7][2]};
    n[1] = x0[6];
    n[2] = (v4){x0[5][1], x0[5][2], x0[5][3], cp[3]};
    n[3] = (v4){cm[4], x1[4][0], x1[4][1], x1[4][2]};
    n[4] = (v4){x1[3][1], x1[3][2], x1[3][3], cp[4]};
    n[5] = (v4){cm[5], xd2[0], xd2[1], xd2[2]};
    n[6] = xd1;
    n[7] = (v4){xd0[1], xd0[2], xd0[3], cp[5]};
    eval_row<NEED_MIN>(x1, n, sel1, mkA1, mkB1, mkC1, glo1, vmin1, Lb, Lc);
}

__global__ __launch_bounds__(256, 2) void bicon_loss_kernel(
    const float* __restrict__ atts, const float* __restrict__ dets,
    const float* __restrict__ target, const float* __restrict__ con,
    float* __restrict__ partial)
{
    const int tid   = (int)threadIdx.x;
    const int bid   = (int)blockIdx.x;
    const int b     = bid >> 7;          // image
    const int br    = bid & 127;         // 4-row band
    const int strip = tid >> 7;          // which row-pair in the band
    const int cg    = tid & 127;         // col-group (4 px)
    const int lane  = tid & 63;
    const int h     = br * 4 + strip * 2;   // even row; thread owns rows h, h+1
    const int w0    = cg << 2;

    const int hm  = (h > 0) ? h - 1 : 0;
    const int hp2 = (h + 2 < HH) ? h + 2 : HH - 1;

    const float mw0   = (w0 == 0) ? 0.f : 1.f;
    const float mw3   = (w0 == WW - 4) ? 0.f : 1.f;
    const float mh0r0 = (h > 0) ? 1.f : 0.f;           // row h has an upper row?
    const float mh1r1 = (h + 1 < HH - 1) ? 1.f : 0.f;  // row h+1 has a lower row?

    const int offC0 = h * WW + w0;
    const int offC1 = offC0 + WW;
    const int offU  = hm * WW + w0;
    const int offD  = hp2 * WW + w0;

    const float* __restrict__ ab = atts + b * CC * HWSZ;
    const float* __restrict__ db = dets + b * CC * HWSZ;
    const float* __restrict__ cb = con  + b * CC * HWSZ;

    // ---- loads in consumption order: con/target, atts, dets ----
    v4 cv0[8], cv1[8];
#pragma unroll
    for (int c = 0; c < 8; ++c) {
        cv0[c] = aload4(cb + c * HWSZ + offC0);
        cv1[c] = aload4(cb + c * HWSZ + offC1);
    }
    v4 tv0 = aload4(target + b * HWSZ + offC0);
    v4 tv1 = aload4(target + b * HWSZ + offC1);

    v4 a0[8], a1[8];
#pragma unroll
    for (int c = 0; c < 8; ++c) {
        a0[c] = aload4(ab + c * HWSZ + offC0);
        a1[c] = aload4(ab + c * HWSZ + offC1);
    }
    v4 au7 = aload4(ab + 7 * HWSZ + offU);
    v4 au6 = aload4(ab + 6 * HWSZ + offU);
    v4 au5 = aload4(ab + 5 * HWSZ + offU);
    v4 ad2 = aload4(ab + 2 * HWSZ + offD);
    v4 ad1 = aload4(ab + 1 * HWSZ + offD);
    v4 ad0 = aload4(ab + 0 * HWSZ + offD);

    v4 d0[8], d1[8];
#pragma unroll
    for (int c = 0; c < 8; ++c) {
        d0[c] = aload4(db + c * HWSZ + offC0);
        d1[c] = aload4(db + c * HWSZ + offC1);
    }
    v4 du7 = aload4(db + 7 * HWSZ + offU);
    v4 du6 = aload4(db + 6 * HWSZ + offU);
    v4 du5 = aload4(db + 5 * HWSZ + offU);
    v4 dd2 = aload4(db + 2 * HWSZ + offD);
    v4 dd1 = aload4(db + 1 * HWSZ + offD);
    v4 dd0 = aload4(db + 0 * HWSZ + offD);

    // con/target -> bitmasks (waits only on the first-issued loads)
    uint32_t sel0 = 0u, sel1 = 0u;
#pragma unroll
    for (int c = 0; c < 8; ++c)
#pragma unroll
        for (int i = 0; i < 4; ++i) {
            if (cv0[c][i] > 0.5f) sel0 |= (1u << (c * 4 + i));
            if (cv1[c][i] > 0.5f) sel1 |= (1u << (c * 4 + i));
        }
    uint32_t tb0 = 0u, tb1 = 0u;
#pragma unroll
    for (int i = 0; i < 4; ++i) {
        if (tv0[i] > 0.5f) tb0 |= (1u << i);
        if (tv1[i] > 0.5f) tb1 |= (1u << i);
    }

    float mkA0[8], mkB0[8], mkC0[8], mkA1[8], mkB1[8], mkC1[8];
    mk_masks(mh0r0, 1.f, mw0, mw3, mkA0, mkB0, mkC0);
    mk_masks(1.f, mh1r1, mw0, mw3, mkA1, mkB1, mkC1);

    float Lb1 = 0.f, Lc1 = 0.f, Lb2 = 0.f, Lc2 = 0.f;
    v4 g1r0, g1r1, g2r0, g2r1, vm2r0, vm2r1, vdum0, vdum1;
    eval_input<false>(ab, a0, a1, au7, au6, au5, ad2, ad1, ad0,
                      offC0, offC1, offU, offD, lane, sel0, sel1,
                      mkA0, mkB0, mkC0, mkA1, mkB1, mkC1,
                      g1r0, g1r1, vdum0, vdum1, Lb1, Lc1);
    eval_input<true >(db, d0, d1, du7, du6, du5, dd2, dd1, dd0,
                      offC0, offC1, offU, offD, lane, sel0, sel1,
                      mkA0, mkB0, mkC0, mkA1, mkB1, mkC1,
                      g2r0, g2r1, vm2r0, vm2r1, Lb2, Lc2);

    // pixel-level: bce(glo1,t) + bce(dec,t), combined log; both rows
    float Lp = 0.f;
#pragma unroll
    for (int r = 0; r < 2; ++r) {
        const uint32_t sel = r ? sel1 : sel0;
        const uint32_t tb  = r ? tb1  : tb0;
        const v4 g1 = r ? g1r1 : g1r0;
        const v4 g2 = r ? g2r1 : g2r0;
        const v4 vm = r ? vm2r1 : vm2r0;
#pragma unroll
        for (int i = 0; i < 4; ++i) {
            const uint32_t mI    = 0x11111111u << i;
            const uint32_t bitsI = sel & mI;
            const bool edge = (bitsI != 0u) && (bitsI != mI);   // 0 < popcount < 8
            const float dec = edge ? (1.0f - vm[i]) : g2[i];
            const bool  ti  = (tb >> i) & 1u;
            const float aa  = ti ? g1[i] : 1.0f - g1[i];
            const float bs  = ti ? dec   : 1.0f - dec;
            Lp += fmaxf(__log2f(aa * bs), LOG2_CLAMP);
        }
    }

    const float wbic = 0.2f / (float)(BB * CC * HWSZ);
    const float wcon = 0.8f / (float)(BB * CC * HWSZ);
    const float wpix = 1.0f / (float)(BB * HWSZ);
    const float ln2  = 0.69314718056f;

    float local = -(wbic * (Lb1 + Lb2) + wcon * (Lc1 + Lc2) + wpix * Lp) * ln2;

#pragma unroll
    for (int off = 32; off > 0; off >>= 1)
        local += __shfl_down(local, off, 64);

    __shared__ float wsum[4];
    const int wid = tid >> 6;
    if (lane == 0) wsum[wid] = local;
    __syncthreads();
    if (tid == 0)
        partial[bid] = wsum[0] + wsum[1] + wsum[2] + wsum[3];
}

// 1024 partials -> out, single block
__global__ __launch_bounds__(256, 1) void reduce_kernel(
    const float* __restrict__ partial, float* __restrict__ out)
{
    const int tid = (int)threadIdx.x;
    float s = 0.f;
#pragma unroll
    for (int i = 0; i < 4; ++i) s += partial[tid + i * 256];
#pragma unroll
    for (int off = 32; off > 0; off >>= 1)
        s += __shfl_down(s, off, 64);
    __shared__ float ws[4];
    if ((tid & 63) == 0) ws[tid >> 6] = s;
    __syncthreads();
    if (tid == 0) out[0] = ws[0] + ws[1] + ws[2] + ws[3];
}

extern "C" void kernel_launch(void* const* d_in, const int* in_sizes, int n_in,
                              void* d_out, int out_size, void* d_ws, size_t ws_size,
                              hipStream_t stream) {
    const float* atts   = (const float*)d_in[0];
    const float* dets   = (const float*)d_in[1];
    const float* target = (const float*)d_in[2];
    const float* con    = (const float*)d_in[3];
    float* out     = (float*)d_out;
    float* partial = (float*)d_ws;          // 1024 * 4 B

    const int nblocks = BB * (HH / 4);      // 1024 blocks, 4 rows x 512 cols each
    bicon_loss_kernel<<<nblocks, 256, 0, stream>>>(atts, dets, target, con, partial);
    reduce_kernel<<<1, 256, 0, stream>>>(partial, out);
}

// Round 7
// 243.364 us; speedup vs baseline: 1.0021x; 1.0021x over previous
//
#include <hip/hip_runtime.h>
#include <stdint.h>

#define BB 8
#define CC 8
#define HH 512
#define WW 512
#define HWSZ (HH * WW)

typedef float v4 __attribute__((ext_vector_type(4)));

#define LOG2_CLAMP -144.26950409f   // -100 / ln2

__device__ __forceinline__ v4 aload4(const float* __restrict__ p) {
    return *(const v4* __restrict__)p;
}

__device__ __forceinline__ v4 sig4(v4 x) {
    v4 r;
#pragma unroll
    for (int i = 0; i < 4; ++i)
        r[i] = __builtin_amdgcn_rcpf(1.0f + __expf(-x[i]));
    return r;
}

// one row's 8 votes; border masks computed inline per-k from 4 scalars
// (k<3: upper row rowm=mh0; k>=5: lower row rowm=mh1; votes {0,3,5} shift
// left => elem0 needs mw0; votes {2,4,7} shift right => elem3 needs mw3)
template <bool NEED_MIN>
__device__ __forceinline__ void eval_row(
    const v4* __restrict__ cr, const v4* __restrict__ nr, uint32_t sel,
    float mh0, float mh1, float mw0, float mw3,
    v4& glo, v4& vmin, float& Lbic, float& Lcon)
{
    const v4 one = {1.f, 1.f, 1.f, 1.f};
    v4 pb0 = one, pb1 = one, pc = one;
    v4 vsum = {0.f, 0.f, 0.f, 0.f};
    if (NEED_MIN) vmin = {1e30f, 1e30f, 1e30f, 1e30f};

#pragma unroll
    for (int k = 0; k < 8; ++k) {
        const float rowm = (k < 3) ? mh0 : ((k >= 5) ? mh1 : 1.f);
        const float m0 = (k == 0 || k == 3 || k == 5) ? mw0 * rowm : rowm;
        const float m3 = (k == 2 || k == 4 || k == 7) ? mw3 * rowm : rowm;
        v4 s = sig4(cr[k]);
        v4 n = sig4(nr[k]);
        n[0] *= m0; n[1] *= rowm; n[2] *= rowm; n[3] *= m3;
        v4 v = s * n;
        vsum += v;
        if (NEED_MIN) vmin = __builtin_elementwise_min(vmin, v);
        v4 av, as;
#pragma unroll
        for (int i = 0; i < 4; ++i) {
            const bool bt = (sel >> (k * 4 + i)) & 1u;
            av[i] = bt ? v[i] : 1.0f - v[i];
            as[i] = bt ? s[i] : 1.0f - s[i];
        }
        if (k < 4) pb0 *= av; else pb1 *= av;
        pc *= as;
    }
    glo = vsum * 0.125f;
#pragma unroll
    for (int i = 0; i < 4; ++i) {
        Lbic += fmaxf(__log2f(pb0[i]), LOG2_CLAMP) + fmaxf(__log2f(pb1[i]), LOG2_CLAMP);
        Lcon += fmaxf(__log2f(pc[i]), LOG2_CLAMP);
    }
}

// One input over the 4x2 patch. Column +-1 shifts built from own/adjacent-lane
// quads (__shfl); lane-edge carries come PRELOADED in gcm/gcp (lane 0 / 63).
// Shuffle garbage at image edges lands only in mask-zeroed elements.
template <bool NEED_MIN>
__device__ __forceinline__ void eval_input(
    const v4* __restrict__ x0, const v4* __restrict__ x1,
    v4 xu7, v4 xu6, v4 xu5, v4 xd2, v4 xd1, v4 xd0,
    const float* __restrict__ gcm, const float* __restrict__ gcp, int lane,
    uint32_t sel0, uint32_t sel1,
    float mh0r0, float mh1r1, float mw0, float mw3,
    v4& glo0, v4& glo1, v4& vmin0, v4& vmin1, float& Lb, float& Lc)
{
    // left carries (col w0-1): order u7, c0_4, c1_2, c0_7, c1_4, d2
    float cm[6];
    {
        float t0 = __shfl(xu7[3],   lane - 1, 64);
        float t1 = __shfl(x0[4][3], lane - 1, 64);
        float t2 = __shfl(x1[2][3], lane - 1, 64);
        float t3 = __shfl(x0[7][3], lane - 1, 64);
        float t4 = __shfl(x1[4][3], lane - 1, 64);
        float t5 = __shfl(xd2[3],   lane - 1, 64);
        const bool e = (lane == 0);
        cm[0] = e ? gcm[0] : t0;  cm[1] = e ? gcm[1] : t1;
        cm[2] = e ? gcm[2] : t2;  cm[3] = e ? gcm[3] : t3;
        cm[4] = e ? gcm[4] : t4;  cm[5] = e ? gcm[5] : t5;
    }
    // right carries (col w0+4): order u5, c0_3, c1_0, c0_5, c1_3, d0
    float cp[6];
    {
        float t0 = __shfl(xu5[0],   lane + 1, 64);
        float t1 = __shfl(x0[3][0], lane + 1, 64);
        float t2 = __shfl(x1[0][0], lane + 1, 64);
        float t3 = __shfl(x0[5][0], lane + 1, 64);
        float t4 = __shfl(x1[3][0], lane + 1, 64);
        float t5 = __shfl(xd0[0],   lane + 1, 64);
        const bool e = (lane == 63);
        cp[0] = e ? gcp[0] : t0;  cp[1] = e ? gcp[1] : t1;
        cp[2] = e ? gcp[2] : t2;  cp[3] = e ? gcp[3] : t3;
        cp[4] = e ? gcp[4] : t4;  cp[5] = e ? gcp[5] : t5;
    }

    v4 n[8];
    // row h votes: U = halo row h-1, D = row h+1 centers (in-register)
    n[0] = (v4){cm[0], xu7[0], xu7[1], xu7[2]};
    n[1] = xu6;
    n[2] = (v4){xu5[1], xu5[2], xu5[3], cp[0]};
    n[3] = (v4){cm[1], x0[4][0], x0[4][1], x0[4][2]};
    n[4] = (v4){x0[3][1], x0[3][2], x0[3][3], cp[1]};
    n[5] = (v4){cm[2], x1[2][0], x1[2][1], x1[2][2]};
    n[6] = x1[1];
    n[7] = (v4){x1[0][1], x1[0][2], x1[0][3], cp[2]};
    eval_row<NEED_MIN>(x0, n, sel0, mh0r0, 1.f, mw0, mw3,
                       glo0, vmin0, Lb, Lc);

    // row h+1 votes: U = row h centers (in-register), D = halo row h+2
    n[0] = (v4){cm[3], x0[7][0], x0[7][1], x0[7][2]};
    n[1] = x0[6];
    n[2] = (v4){x0[5][1], x0[5][2], x0[5][3], cp[3]};
    n[3] = (v4){cm[4], x1[4][0], x1[4][1], x1[4][2]};
    n[4] = (v4){x1[3][1], x1[3][2], x1[3][3], cp[4]};
    n[5] = (v4){cm[5], xd2[0], xd2[1], xd2[2]};
    n[6] = xd1;
    n[7] = (v4){xd0[1], xd0[2], xd0[3], cp[5]};
    eval_row<NEED_MIN>(x1, n, sel1, 1.f, mh1r1, mw0, mw3,
                       glo1, vmin1, Lb, Lc);
}

__global__ void __launch_bounds__(256)
__attribute__((amdgpu_waves_per_eu(2, 2)))   // pin 256-VGPR budget; forbid R6's cap-at-128-and-spill
bicon_loss_kernel(
    const float* __restrict__ atts, const float* __restrict__ dets,
    const float* __restrict__ target, const float* __restrict__ con,
    float* __restrict__ partial)
{
    const int tid   = (int)threadIdx.x;
    const int bid   = (int)blockIdx.x;
    const int b     = bid >> 7;          // image
    const int br    = bid & 127;         // 4-row band
    const int strip = tid >> 7;          // which row-pair in the band
    const int cg    = tid & 127;         // col-group (4 px)
    const int lane  = tid & 63;
    const int h     = br * 4 + strip * 2;   // even row; thread owns rows h, h+1
    const int w0    = cg << 2;

    const int hm  = (h > 0) ? h - 1 : 0;
    const int hp2 = (h + 2 < HH) ? h + 2 : HH - 1;

    const float mw0   = (w0 == 0) ? 0.f : 1.f;
    const float mw3   = (w0 == WW - 4) ? 0.f : 1.f;
    const float mh0r0 = (h > 0) ? 1.f : 0.f;
    const float mh1r1 = (h + 1 < HH - 1) ? 1.f : 0.f;

    const int offC0 = h * WW + w0;
    const int offC1 = offC0 + WW;
    const int offU  = hm * WW + w0;
    const int offD  = hp2 * WW + w0;

    const float* __restrict__ ab = atts + b * CC * HWSZ;
    const float* __restrict__ db = dets + b * CC * HWSZ;
    const float* __restrict__ cb = con  + b * CC * HWSZ;

    // ---- phase 1: con/target (consumed first) ----
    v4 cv0[8], cv1[8];
#pragma unroll
    for (int c = 0; c < 8; ++c) {
        cv0[c] = aload4(cb + c * HWSZ + offC0);
        cv1[c] = aload4(cb + c * HWSZ + offC1);
    }
    v4 tv0 = aload4(target + b * HWSZ + offC0);
    v4 tv1 = aload4(target + b * HWSZ + offC1);

    // ---- phase 2: atts bulk + lane-edge carries (BEFORE dets, so the
    // in-order vmcnt wait for atts doesn't drain dets) ----
    v4 a0[8], a1[8];
#pragma unroll
    for (int c = 0; c < 8; ++c) {
        a0[c] = aload4(ab + c * HWSZ + offC0);
        a1[c] = aload4(ab + c * HWSZ + offC1);
    }
    v4 au7 = aload4(ab + 7 * HWSZ + offU);
    v4 au6 = aload4(ab + 6 * HWSZ + offU);
    v4 au5 = aload4(ab + 5 * HWSZ + offU);
    v4 ad2 = aload4(ab + 2 * HWSZ + offD);
    v4 ad1 = aload4(ab + 1 * HWSZ + offD);
    v4 ad0 = aload4(ab + 0 * HWSZ + offD);
    float acm[6] = {}, acp[6] = {};
    if (lane == 0) {   // left neighbor never in own wave; valid addr (ch>=2)
        acm[0] = ab[7 * HWSZ + offU  - 1];
        acm[1] = ab[4 * HWSZ + offC0 - 1];
        acm[2] = ab[2 * HWSZ + offC1 - 1];
        acm[3] = ab[7 * HWSZ + offC0 - 1];
        acm[4] = ab[4 * HWSZ + offC1 - 1];
        acm[5] = ab[2 * HWSZ + offD  - 1];
    }
    if (lane == 63) {  // right neighbor never in own wave; valid addr (ch<=5)
        acp[0] = ab[5 * HWSZ + offU  + 4];
        acp[1] = ab[3 * HWSZ + offC0 + 4];
        acp[2] = ab[0 * HWSZ + offC1 + 4];
        acp[3] = ab[5 * HWSZ + offC0 + 4];
        acp[4] = ab[3 * HWSZ + offC1 + 4];
        acp[5] = ab[0 * HWSZ + offD  + 4];
    }

    // ---- phase 3: sel/tb from cv (waits only the first 18 loads; frees 66 regs) ----
    uint32_t sel0 = 0u, sel1 = 0u;
#pragma unroll
    for (int c = 0; c < 8; ++c)
#pragma unroll
        for (int i = 0; i < 4; ++i) {
            if (cv0[c][i] > 0.5f) sel0 |= (1u << (c * 4 + i));
            if (cv1[c][i] > 0.5f) sel1 |= (1u << (c * 4 + i));
        }
    uint32_t tb0 = 0u, tb1 = 0u;
#pragma unroll
    for (int i = 0; i < 4; ++i) {
        if (tv0[i] > 0.5f) tb0 |= (1u << i);
        if (tv1[i] > 0.5f) tb1 |= (1u << i);
    }

    // ---- phase 4: dets bulk + carries ----
    v4 d0[8], d1[8];
#pragma unroll
    for (int c = 0; c < 8; ++c) {
        d0[c] = aload4(db + c * HWSZ + offC0);
        d1[c] = aload4(db + c * HWSZ + offC1);
    }
    v4 du7 = aload4(db + 7 * HWSZ + offU);
    v4 du6 = aload4(db + 6 * HWSZ + offU);
    v4 du5 = aload4(db + 5 * HWSZ + offU);
    v4 dd2 = aload4(db + 2 * HWSZ + offD);
    v4 dd1 = aload4(db + 1 * HWSZ + offD);
    v4 dd0 = aload4(db + 0 * HWSZ + offD);
    float dcm[6] = {}, dcp[6] = {};
    if (lane == 0) {
        dcm[0] = db[7 * HWSZ + offU  - 1];
        dcm[1] = db[4 * HWSZ + offC0 - 1];
        dcm[2] = db[2 * HWSZ + offC1 - 1];
        dcm[3] = db[7 * HWSZ + offC0 - 1];
        dcm[4] = db[4 * HWSZ + offC1 - 1];
        dcm[5] = db[2 * HWSZ + offD  - 1];
    }
    if (lane == 63) {
        dcp[0] = db[5 * HWSZ + offU  + 4];
        dcp[1] = db[3 * HWSZ + offC0 + 4];
        dcp[2] = db[0 * HWSZ + offC1 + 4];
        dcp[3] = db[5 * HWSZ + offC0 + 4];
        dcp[4] = db[3 * HWSZ + offC1 + 4];
        dcp[5] = db[0 * HWSZ + offD  + 4];
    }

    // ---- phase 5: atts eval (dets loads still in flight) ----
    float Lb1 = 0.f, Lc1 = 0.f, Lb2 = 0.f, Lc2 = 0.f;
    v4 g1r0, g1r1, g2r0, g2r1, vm2r0, vm2r1, vdum0, vdum1;
    eval_input<false>(a0, a1, au7, au6, au5, ad2, ad1, ad0,
                      acm, acp, lane, sel0, sel1,
                      mh0r0, mh1r1, mw0, mw3,
                      g1r0, g1r1, vdum0, vdum1, Lb1, Lc1);

    // ---- phase 6: dets eval ----
    eval_input<true >(d0, d1, du7, du6, du5, dd2, dd1, dd0,
                      dcm, dcp, lane, sel0, sel1,
                      mh0r0, mh1r1, mw0, mw3,
                      g2r0, g2r1, vm2r0, vm2r1, Lb2, Lc2);

    // pixel-level: bce(glo1,t) + bce(dec,t), combined log; both rows
    float Lp = 0.f;
#pragma unroll
    for (int r = 0; r < 2; ++r) {
        const uint32_t sel = r ? sel1 : sel0;
        const uint32_t tb  = r ? tb1  : tb0;
        const v4 g1 = r ? g1r1 : g1r0;
        const v4 g2 = r ? g2r1 : g2r0;
        const v4 vm = r ? vm2r1 : vm2r0;
#pragma unroll
        for (int i = 0; i < 4; ++i) {
            const uint32_t mI    = 0x11111111u << i;
            const uint32_t bitsI = sel & mI;
            const bool edge = (bitsI != 0u) && (bitsI != mI);   // 0 < popcount < 8
            const float dec = edge ? (1.0f - vm[i]) : g2[i];
            const bool  ti  = (tb >> i) & 1u;
            const float aa  = ti ? g1[i] : 1.0f - g1[i];
            const float bs  = ti ? dec   : 1.0f - dec;
            Lp += fmaxf(__log2f(aa * bs), LOG2_CLAMP);
        }
    }

    const float wbic = 0.2f / (float)(BB * CC * HWSZ);
    const float wcon = 0.8f / (float)(BB * CC * HWSZ);
    const float wpix = 1.0f / (float)(BB * HWSZ);
    const float ln2  = 0.69314718056f;

    float local = -(wbic * (Lb1 + Lb2) + wcon * (Lc1 + Lc2) + wpix * Lp) * ln2;

#pragma unroll
    for (int off = 32; off > 0; off >>= 1)
        local += __shfl_down(local, off, 64);

    __shared__ float wsum[4];
    const int wid = tid >> 6;
    if (lane == 0) wsum[wid] = local;
    __syncthreads();
    if (tid == 0)
        partial[bid] = wsum[0] + wsum[1] + wsum[2] + wsum[3];
}

// 1024 partials -> out, single block
__global__ __launch_bounds__(256, 1) void reduce_kernel(
    const float* __restrict__ partial, float* __restrict__ out)
{
    const int tid = (int)threadIdx.x;
    float s = 0.f;
#pragma unroll
    for (int i = 0; i < 4; ++i) s += partial[tid + i * 256];
#pragma unroll
    for (int off = 32; off > 0; off >>= 1)
        s += __shfl_down(s, off, 64);
    __shared__ float ws[4];
    if ((tid & 63) == 0) ws[tid >> 6] = s;
    __syncthreads();
    if (tid == 0) out[0] = ws[0] + ws[1] + ws[2] + ws[3];
}

extern "C" void kernel_launch(void* const* d_in, const int* in_sizes, int n_in,
                              void* d_out, int out_size, void* d_ws, size_t ws_size,
                              hipStream_t stream) {
    const float* atts   = (const float*)d_in[0];
    const float* dets   = (const float*)d_in[1];
    const float* target = (const float*)d_in[2];
    const float* con    = (const float*)d_in[3];
    float* out     = (float*)d_out;
    float* partial = (float*)d_ws;          // 1024 * 4 B

    const int nblocks = BB * (HH / 4);      // 1024 blocks, 4 rows x 512 cols each
    bicon_loss_kernel<<<nblocks, 256, 0, stream>>>(atts, dets, target, con, partial);
    reduce_kernel<<<1, 256, 0, stream>>>(partial, out);
}

// Round 8
// 202.713 us; speedup vs baseline: 1.2030x; 1.2005x over previous
//
#include <hip/hip_runtime.h>
#include <stdint.h>

#define BB 8
#define CC 8
#define HH 512
#define WW 512
#define HWSZ (HH * WW)

typedef float v4 __attribute__((ext_vector_type(4)));

#define LOG2_CLAMP -144.26950409f   // -100 / ln2

__device__ __forceinline__ v4 aload4(const float* __restrict__ p) {
    return *(const v4* __restrict__)p;
}

__device__ __forceinline__ v4 sig4(v4 x) {
    v4 r;
#pragma unroll
    for (int i = 0; i < 4; ++i)
        r[i] = __builtin_amdgcn_rcpf(1.0f + __expf(-x[i]));
    return r;
}

__device__ __forceinline__ v4 shflv4(v4 v, int src) {
    v4 r;
#pragma unroll
    for (int i = 0; i < 4; ++i) r[i] = __shfl(v[i], src, 64);
    return r;
}

// one row's 8 votes; border masks inline from 4 scalars (identical to R5/R7,
// which passed bit-exact). k<3: needs row above (mh0); k>=5: row below (mh1);
// votes {0,3,5} shift left => elem0 x mw0; {2,4,7} shift right => elem3 x mw3.
template <bool NEED_MIN>
__device__ __forceinline__ void eval_row(
    const v4* __restrict__ cr, const v4* __restrict__ nr, uint32_t sel,
    float mh0, float mh1, float mw0, float mw3,
    v4& glo, v4& vmin, float& Lbic, float& Lcon)
{
    const v4 one = {1.f, 1.f, 1.f, 1.f};
    v4 pb0 = one, pb1 = one, pc = one;
    v4 vsum = {0.f, 0.f, 0.f, 0.f};
    if (NEED_MIN) vmin = {1e30f, 1e30f, 1e30f, 1e30f};

#pragma unroll
    for (int k = 0; k < 8; ++k) {
        const float rowm = (k < 3) ? mh0 : ((k >= 5) ? mh1 : 1.f);
        const float m0 = (k == 0 || k == 3 || k == 5) ? mw0 * rowm : rowm;
        const float m3 = (k == 2 || k == 4 || k == 7) ? mw3 * rowm : rowm;
        v4 s = sig4(cr[k]);
        v4 n = sig4(nr[k]);
        n[0] *= m0; n[1] *= rowm; n[2] *= rowm; n[3] *= m3;
        v4 v = s * n;
        vsum += v;
        if (NEED_MIN) vmin = __builtin_elementwise_min(vmin, v);
        v4 av, as;
#pragma unroll
        for (int i = 0; i < 4; ++i) {
            const bool bt = (sel >> (k * 4 + i)) & 1u;
            av[i] = bt ? v[i] : 1.0f - v[i];
            as[i] = bt ? s[i] : 1.0f - s[i];
        }
        if (k < 4) pb0 *= av; else pb1 *= av;
        pc *= as;
    }
    glo = vsum * 0.125f;
#pragma unroll
    for (int i = 0; i < 4; ++i) {
        Lbic += fmaxf(__log2f(pb0[i]), LOG2_CLAMP) + fmaxf(__log2f(pb1[i]), LOG2_CLAMP);
        Lcon += fmaxf(__log2f(pc[i]), LOG2_CLAMP);
    }
}

// One input for one thread's row (4 px). Wave layout: lanes 0-31 = row h
// (rsel=0), lanes 32-63 = row h+1 (rsel=1), same column groups. Vertical
// neighbors for the IN-PAIR row come from the other half-wave via
// __shfl_xor(32); the outer halo row (h-1 for rsel=0 / h+2's... h+1 for
// rsel=1) comes from hq[3] loaded from memory. Column +-1 shifts via lane+-1
// shuffles; cg-edge lanes (cg==0/31) use preloaded memory carries cL/cR.
// Shuffle garbage at image edges lands only in mask-zeroed elements.
template <bool NEED_MIN>
__device__ __forceinline__ void eval_input(
    const v4* __restrict__ x, const v4* __restrict__ hq,
    const float* __restrict__ cL, const float* __restrict__ cR,
    int lane, int rsel, int cg, uint32_t sel,
    float mh0, float mh1, float mw0, float mw3,
    v4& glo, v4& vmin, float& Lb, float& Lc)
{
    const int po = lane ^ 32;   // partner lane in the other row, same cols
    // vertical row quads (channel 7-k at row h-1 / h+1)
    v4 s7 = shflv4(x[7], po), s6 = shflv4(x[6], po), s5 = shflv4(x[5], po);
    v4 s2 = shflv4(x[2], po), s1 = shflv4(x[1], po), s0 = shflv4(x[0], po);
    const v4 up7 = rsel ? s7 : hq[0];   // ch7 @ row h-1
    const v4 up6 = rsel ? s6 : hq[1];   // ch6 @ row h-1
    const v4 up5 = rsel ? s5 : hq[2];   // ch5 @ row h-1
    const v4 dn2 = rsel ? hq[0] : s2;   // ch2 @ row h+1
    const v4 dn1 = rsel ? hq[1] : s1;   // ch1 @ row h+1
    const v4 dn0 = rsel ? hq[2] : s0;   // ch0 @ row h+1

    // left carries: element at col w0-1 of (up7, x[4]@h, dn2)
    float l0 = __shfl(up7[3],  lane - 1, 64);
    float l1 = __shfl(x[4][3], lane - 1, 64);
    float l2 = __shfl(dn2[3],  lane - 1, 64);
    if (cg == 0) { l0 = cL[0]; l1 = cL[1]; l2 = cL[2]; }
    // right carries: element at col w0+4 of (up5, x[3]@h, dn0)
    float r0 = __shfl(up5[0],  lane + 1, 64);
    float r1 = __shfl(x[3][0], lane + 1, 64);
    float r2 = __shfl(dn0[0],  lane + 1, 64);
    if (cg == 31) { r0 = cR[0]; r1 = cR[1]; r2 = cR[2]; }

    v4 n[8];
    n[0] = (v4){l0, up7[0], up7[1], up7[2]};          // ch7, h-1, shift left
    n[1] = up6;                                        // ch6, h-1
    n[2] = (v4){up5[1], up5[2], up5[3], r0};          // ch5, h-1, shift right
    n[3] = (v4){l1, x[4][0], x[4][1], x[4][2]};       // ch4, h,   shift left
    n[4] = (v4){x[3][1], x[3][2], x[3][3], r1};       // ch3, h,   shift right
    n[5] = (v4){l2, dn2[0], dn2[1], dn2[2]};          // ch2, h+1, shift left
    n[6] = dn1;                                        // ch1, h+1
    n[7] = (v4){dn0[1], dn0[2], dn0[3], r2};          // ch0, h+1, shift right
    eval_row<NEED_MIN>(x, n, sel, mh0, mh1, mw0, mw3, glo, vmin, Lb, Lc);
}

__global__ __launch_bounds__(256, 2) void bicon_loss_kernel(
    const float* __restrict__ atts, const float* __restrict__ dets,
    const float* __restrict__ target, const float* __restrict__ con,
    float* __restrict__ partial)
{
    const int tid  = (int)threadIdx.x;
    const int bid  = (int)blockIdx.x;
    const int wave = tid >> 6;
    const int lane = tid & 63;
    const int rsel = lane >> 5;          // 0: row h0+2w, 1: row h0+2w+1
    const int cg   = lane & 31;          // column quad within the 128-col strip

    const int b    = bid >> 8;           // image
    const int rem  = bid & 255;          // 64 row-groups x 4 col-strips
    const int h0   = (rem >> 2) << 3;    // 8 rows per block
    const int c0   = (rem & 3) << 7;     // 128 cols per block

    const int h  = h0 + (wave << 1) + rsel;
    const int w0 = c0 + (cg << 2);

    const float mw0 = (w0 == 0) ? 0.f : 1.f;
    const float mw3 = (w0 == WW - 4) ? 0.f : 1.f;
    const float mh0 = (h > 0) ? 1.f : 0.f;
    const float mh1 = (h < HH - 1) ? 1.f : 0.f;

    const int offC  = h * WW + w0;
    const int hU    = (h > 0) ? h - 1 : 0;            // clamped; masked at edges
    const int hD    = (h < HH - 1) ? h + 1 : HH - 1;
    const int hHalo = rsel ? hD : hU;                 // outer halo row
    const int offH  = hHalo * WW + w0;
    const int colm  = (w0 > 0) ? w0 - 1 : 0;
    const int colp  = (w0 < WW - 4) ? w0 + 4 : WW - 1;

    const float* __restrict__ ab = atts + b * CC * HWSZ;
    const float* __restrict__ db = dets + b * CC * HWSZ;
    const float* __restrict__ cb = con  + b * CC * HWSZ;

    // halo channels for this half-wave: rsel=0 -> up row ch{7,6,5};
    // rsel=1 -> down row ch{2,1,0}
    const int hc0 = rsel ? 2 : 7;
    const int hc1 = rsel ? 1 : 6;
    const int hc2 = rsel ? 0 : 5;

    // ---- phase 1: con/target (consumed first: sel gates every vote) ----
    v4 cv[8];
#pragma unroll
    for (int c = 0; c < 8; ++c) cv[c] = aload4(cb + c * HWSZ + offC);
    v4 tv = aload4(target + b * HWSZ + offC);

    // ---- phase 2: atts bulk (8 center + 3 halo) + edge carries ----
    v4 ax[8], ahq[3];
#pragma unroll
    for (int c = 0; c < 8; ++c) ax[c] = aload4(ab + c * HWSZ + offC);
    ahq[0] = aload4(ab + hc0 * HWSZ + offH);
    ahq[1] = aload4(ab + hc1 * HWSZ + offH);
    ahq[2] = aload4(ab + hc2 * HWSZ + offH);
    float acL[3] = {}, acR[3] = {};
    if (cg == 0) {           // col w0-1 (outside the wave's strip)
        acL[0] = ab[7 * HWSZ + hU * WW + colm];
        acL[1] = ab[4 * HWSZ + h  * WW + colm];
        acL[2] = ab[2 * HWSZ + hD * WW + colm];
    }
    if (cg == 31) {          // col w0+4
        acR[0] = ab[5 * HWSZ + hU * WW + colp];
        acR[1] = ab[3 * HWSZ + h  * WW + colp];
        acR[2] = ab[0 * HWSZ + hD * WW + colp];
    }

    // ---- phase 3: sel/tb (waits only the first-issued loads; frees 33 regs) ----
    uint32_t sel = 0u;
#pragma unroll
    for (int c = 0; c < 8; ++c)
#pragma unroll
        for (int i = 0; i < 4; ++i)
            if (cv[c][i] > 0.5f) sel |= (1u << (c * 4 + i));
    uint32_t tb = 0u;
#pragma unroll
    for (int i = 0; i < 4; ++i)
        if (tv[i] > 0.5f) tb |= (1u << i);

    // ---- phase 4: dets bulk + carries (in flight during atts eval) ----
    v4 dx[8], dhq[3];
#pragma unroll
    for (int c = 0; c < 8; ++c) dx[c] = aload4(db + c * HWSZ + offC);
    dhq[0] = aload4(db + hc0 * HWSZ + offH);
    dhq[1] = aload4(db + hc1 * HWSZ + offH);
    dhq[2] = aload4(db + hc2 * HWSZ + offH);
    float dcL[3] = {}, dcR[3] = {};
    if (cg == 0) {
        dcL[0] = db[7 * HWSZ + hU * WW + colm];
        dcL[1] = db[4 * HWSZ + h  * WW + colm];
        dcL[2] = db[2 * HWSZ + hD * WW + colm];
    }
    if (cg == 31) {
        dcR[0] = db[5 * HWSZ + hU * WW + colp];
        dcR[1] = db[3 * HWSZ + h  * WW + colp];
        dcR[2] = db[0 * HWSZ + hD * WW + colp];
    }

    // ---- phase 5: atts eval ---- (dets loads still draining)
    float Lb1 = 0.f, Lc1 = 0.f, Lb2 = 0.f, Lc2 = 0.f;
    v4 glo1, glo2, vmin2, vdum;
    eval_input<false>(ax, ahq, acL, acR, lane, rsel, cg, sel,
                      mh0, mh1, mw0, mw3, glo1, vdum, Lb1, Lc1);

    // ---- phase 6: dets eval ----
    eval_input<true >(dx, dhq, dcL, dcR, lane, rsel, cg, sel,
                      mh0, mh1, mw0, mw3, glo2, vmin2, Lb2, Lc2);

    // ---- pixel-level: bce(glo1,t) + bce(dec,t), combined log ----
    float Lp = 0.f;
#pragma unroll
    for (int i = 0; i < 4; ++i) {
        const uint32_t mI    = 0x11111111u << i;
        const uint32_t bitsI = sel & mI;
        const bool edge = (bitsI != 0u) && (bitsI != mI);   // 0 < popcount < 8
        const float dec = edge ? (1.0f - vmin2[i]) : glo2[i];
        const bool  ti  = (tb >> i) & 1u;
        const float aa  = ti ? glo1[i] : 1.0f - glo1[i];
        const float bs  = ti ? dec     : 1.0f - dec;
        Lp += fmaxf(__log2f(aa * bs), LOG2_CLAMP);
    }

    const float wbic = 0.2f / (float)(BB * CC * HWSZ);
    const float wcon = 0.8f / (float)(BB * CC * HWSZ);
    const float wpix = 1.0f / (float)(BB * HWSZ);
    const float ln2  = 0.69314718056f;

    float local = -(wbic * (Lb1 + Lb2) + wcon * (Lc1 + Lc2) + wpix * Lp) * ln2;

#pragma unroll
    for (int off = 32; off > 0; off >>= 1)
        local += __shfl_down(local, off, 64);

    __shared__ float wsum[4];
    if (lane == 0) wsum[tid >> 6] = local;
    __syncthreads();
    if (tid == 0)
        partial[bid] = wsum[0] + wsum[1] + wsum[2] + wsum[3];
}

// 2048 partials -> out, single block
__global__ __launch_bounds__(256, 1) void reduce_kernel(
    const float* __restrict__ partial, float* __restrict__ out)
{
    const int tid = (int)threadIdx.x;
    float s = 0.f;
#pragma unroll
    for (int i = 0; i < 8; ++i) s += partial[tid + i * 256];
#pragma unroll
    for (int off = 32; off > 0; off >>= 1)
        s += __shfl_down(s, off, 64);
    __shared__ float ws[4];
    if ((tid & 63) == 0) ws[tid >> 6] = s;
    __syncthreads();
    if (tid == 0) out[0] = ws[0] + ws[1] + ws[2] + ws[3];
}

extern "C" void kernel_launch(void* const* d_in, const int* in_sizes, int n_in,
                              void* d_out, int out_size, void* d_ws, size_t ws_size,
                              hipStream_t stream) {
    const float* atts   = (const float*)d_in[0];
    const float* dets   = (const float*)d_in[1];
    const float* target = (const float*)d_in[2];
    const float* con    = (const float*)d_in[3];
    float* out     = (float*)d_out;
    float* partial = (float*)d_ws;          // 2048 * 4 B

    const int nblocks = BB * (HH / 8) * (WW / 128);   // 2048 blocks, 8x128 px
    bicon_loss_kernel<<<nblocks, 256, 0, stream>>>(atts, dets, target, con, partial);
    reduce_kernel<<<1, 256, 0, stream>>>(partial, out);
}